// Round 4
// baseline (552.758 us; speedup 1.0000x reference)
//
#include <hip/hip_runtime.h>
#include <hip/hip_bf16.h>

#define BATCH 16
#define CINC 96
#define HGT 112
#define WID 112
#define HW 12544          // 112*112
#define C1N 192
#define C2N 384
#define EPSV 1e-5f

typedef _Float16 f16x8 __attribute__((ext_vector_type(8)));
typedef _Float16 f16x4 __attribute__((ext_vector_type(4)));
typedef float    f32x4 __attribute__((ext_vector_type(4)));

// d_ws layout (float offsets unless noted). Total ~118 KB.
#define WS_S      0        // 16*384 f32 u-sums (zeroed each launch)
#define WS_A1B1   6144     // 16*192 f32
#define WS_W1F    9216     // 192*3
#define WS_B1F    9792     // 192
#define WS_W2F    9984     // 384*3
#define WS_B2F    11136    // 384
#define WS_S3     11520    // 96
#define WS_B3     11616    // 96
#define WS_WP_BYTES (11712*4)   // f16 Wp[96][384] (shuffle folded)

// ---------------- prep: fold BN into weights, permute+cast pw weights ----------
__global__ void k_prep(const float* __restrict__ wdw1, const float* __restrict__ g1,
                       const float* __restrict__ bb1, const float* __restrict__ m1,
                       const float* __restrict__ v1,
                       const float* __restrict__ wdw2, const float* __restrict__ g2,
                       const float* __restrict__ bb2, const float* __restrict__ m2,
                       const float* __restrict__ v2,
                       const float* __restrict__ wpw, const float* __restrict__ g3,
                       const float* __restrict__ bb3, const float* __restrict__ m3,
                       const float* __restrict__ v3,
                       float* ws)
{
    int t = threadIdx.x;
    float* w1f = ws + WS_W1F; float* b1f = ws + WS_B1F;
    float* w2f = ws + WS_W2F; float* b2f = ws + WS_B2F;
    float* s3  = ws + WS_S3;  float* b3f = ws + WS_B3;
    _Float16* wp = (_Float16*)((char*)ws + WS_WP_BYTES);

    for (int c = t; c < C1N; c += 256) {
        float s = g1[c] / sqrtf(v1[c] + EPSV);
        w1f[c*3+0] = wdw1[c*3+0] * s;
        w1f[c*3+1] = wdw1[c*3+1] * s;
        w1f[c*3+2] = wdw1[c*3+2] * s;
        b1f[c] = bb1[c] - m1[c] * s;
    }
    for (int c = t; c < C2N; c += 256) {
        float s = g2[c] / sqrtf(v2[c] + EPSV);
        w2f[c*3+0] = wdw2[c*3+0] * s;
        w2f[c*3+1] = wdw2[c*3+1] * s;
        w2f[c*3+2] = wdw2[c*3+2] * s;
        b2f[c] = bb2[c] - m2[c] * s;
    }
    for (int c = t; c < CINC; c += 256) {
        float s = g3[c] / sqrtf(v3[c] + EPSV);
        s3[c] = s; b3f[c] = bb3[c] - m3[c] * s;
    }
    // Wp[m][k] = w_pw[m][(k%64)*6 + k/64]  (folds channel shuffle groups=6)
    for (int idx = t; idx < CINC * C2N; idx += 256) {
        int m = idx / C2N, k = idx - m * C2N;
        int o = (k & 63) * 6 + (k >> 6);
        wp[idx] = (_Float16)wpw[m * C2N + o];
    }
}

// ---------------- pass A: per-channel u sums, all fp32 (feeds the mean path) --
// one block per (b, cin); accumulates S[b][4c..4c+3] = sum over positions of u
__global__ __launch_bounds__(256) void k_sums(const float* __restrict__ x,
                                              const float* __restrict__ ws,
                                              float* __restrict__ S)
{
    int b = blockIdx.x / CINC;
    int c = blockIdx.x - b * CINC;
    const float* w1f = ws + WS_W1F; const float* b1f = ws + WS_B1F;
    const float* w2f = ws + WS_W2F; const float* b2f = ws + WS_B2F;
    const float* xc = x + ((long)(b * CINC + c)) * HW;

    int c1a = c * 2;
    float wa0 = w1f[c1a*3+0], wa1 = w1f[c1a*3+1], wa2 = w1f[c1a*3+2], ba = b1f[c1a];
    float wb0 = w1f[c1a*3+3], wb1 = w1f[c1a*3+4], wb2 = w1f[c1a*3+5], bbv = b1f[c1a+1];
    int c2b = c * 4;
    float w2t[12], b2t[4];
    #pragma unroll
    for (int j = 0; j < 4; ++j) {
        w2t[j*3+0] = w2f[(c2b+j)*3+0];
        w2t[j*3+1] = w2f[(c2b+j)*3+1];
        w2t[j*3+2] = w2f[(c2b+j)*3+2];
        b2t[j] = b2f[c2b+j];
    }

    float acc[4] = {0.f, 0.f, 0.f, 0.f};
    for (int pos = threadIdx.x; pos < HW; pos += 256) {
        int y = pos / WID, xx = pos - y * WID;
        float xv[9];
        #pragma unroll
        for (int dy = 0; dy < 3; ++dy) {
            int yy = y + dy - 1;
            bool yok = (unsigned)yy < (unsigned)HGT;
            const float* rp = xc + yy * WID;
            #pragma unroll
            for (int dx = 0; dx < 3; ++dx) {
                int x2 = xx + dx - 1;
                xv[dy*3+dx] = (yok && (unsigned)x2 < (unsigned)WID) ? rp[x2] : 0.f;
            }
        }
        // h1 = BN1(conv1(x)) at columns xx-1, xx, xx+1.
        // conv2's W-padding zero-pads the BN1 OUTPUT -> out-of-range columns are 0.
        float h1a[3], h1b[3];
        #pragma unroll
        for (int dx = 0; dx < 3; ++dx) {
            h1a[dx] = fmaf(wa0, xv[dx], fmaf(wa1, xv[3+dx], fmaf(wa2, xv[6+dx], ba)));
            h1b[dx] = fmaf(wb0, xv[dx], fmaf(wb1, xv[3+dx], fmaf(wb2, xv[6+dx], bbv)));
        }
        if (xx == 0)       { h1a[0] = 0.f; h1b[0] = 0.f; }
        if (xx == WID - 1) { h1a[2] = 0.f; h1b[2] = 0.f; }
        #pragma unroll
        for (int j = 0; j < 4; ++j) {
            float p0 = (j < 2) ? h1a[0] : h1b[0];
            float p1 = (j < 2) ? h1a[1] : h1b[1];
            float p2 = (j < 2) ? h1a[2] : h1b[2];
            float tv = fmaf(w2t[j*3+0], p0, fmaf(w2t[j*3+1], p1, fmaf(w2t[j*3+2], p2, b2t[j])));
            acc[j] += fminf(fmaxf(tv, 0.f), 6.f);
        }
    }
    // wave reduce (64 lanes) then one atomic per wave per channel
    #pragma unroll
    for (int j = 0; j < 4; ++j) {
        float sv = acc[j];
        sv += __shfl_xor(sv, 1);
        sv += __shfl_xor(sv, 2);
        sv += __shfl_xor(sv, 4);
        sv += __shfl_xor(sv, 8);
        sv += __shfl_xor(sv, 16);
        sv += __shfl_xor(sv, 32);
        if ((threadIdx.x & 63) == 0) atomicAdd(&S[b * C2N + c2b + j], sv);
    }
}

// ---------------- mean (via S + fp32 Wp) -> MLP -> gates a1,b1 ----------------
__global__ void k_fc(const float* __restrict__ S, const float* __restrict__ ws,
                     const float* __restrict__ wpw,
                     const float* __restrict__ fc1w, const float* __restrict__ fc1b,
                     const float* __restrict__ fc2w, const float* __restrict__ fc2b,
                     float* __restrict__ a1b1)
{
    __shared__ float Ss[BATCH][C2N];
    __shared__ float mean_s[BATCH][CINC];
    __shared__ float mid[BATCH][24];
    int t = threadIdx.x;   // 384
    for (int i = t; i < BATCH * C2N; i += 384) Ss[i / C2N][i - (i / C2N) * C2N] = S[i];
    __syncthreads();
    const float* s3 = ws + WS_S3; const float* b3f = ws + WS_B3;
    for (int i = t; i < BATCH * CINC; i += 384) {
        int b = i / CINC, m = i - b * CINC;
        float acc = 0.f;
        for (int k = 0; k < C2N; ++k) {
            int o = (k & 63) * 6 + (k >> 6);
            acc = fmaf(wpw[m * C2N + o], Ss[b][k], acc);
        }
        mean_s[b][m] = fmaf(s3[m], acc * (1.0f / 12544.0f), b3f[m]);
    }
    __syncthreads();
    {
        int b = t / 24, i = t - b * 24;
        float d = fc1b[i];
        for (int c = 0; c < CINC; ++c) d = fmaf(fc1w[i * CINC + c], mean_s[b][c], d);
        mid[b][i] = fmaxf(d, 0.f);
    }
    __syncthreads();
    for (int idx = t; idx < BATCH * 192; idx += 384) {
        int b = idx / 192, o = idx - b * 192;
        float d = fc2b[o];
        for (int j = 0; j < 24; ++j) d = fmaf(fc2w[o * 24 + j], mid[b][j], d);
        float y = fminf(fmaxf(d + 3.f, 0.f), 6.f) * (1.f / 6.f);
        y = (y - 0.5f) * 4.f;
        a1b1[idx] = (o < CINC) ? (y + 1.f) : y;
    }
}

// ---------------- pass B: u (fp16 LDS) -> MFMA GEMM -> bn3 -> gates+shuffle+x --
// tile = 4 rows x 16 cols (64 positions), 256 threads = 4 waves; h stays on-chip
__global__ __launch_bounds__(256) void k_main2(const float* __restrict__ x,
                                               const float* __restrict__ ws,
                                               const float* __restrict__ a1b1,
                                               float* __restrict__ out)
{
    __shared__ __align__(16) _Float16 u_lds[64][392];   // 50176 B; h_s aliases this
    int t   = threadIdx.x;
    int bid = blockIdx.x;
    int b    = bid / 196;
    int tile = bid - b * 196;
    int y0 = (tile / 7) * 4;
    int x0 = (tile % 7) * 16;

    const float* w1f = ws + WS_W1F; const float* b1f = ws + WS_B1F;
    const float* w2f = ws + WS_W2F; const float* b2f = ws + WS_B2F;

    int pos = t & 63, wv = t >> 6;
    int py = pos >> 4, px = pos & 15;
    int gy = y0 + py, gx = x0 + px;

    // phase 1: compute u (384 ch) for the 64 positions into LDS (fp16)
    #pragma unroll 2
    for (int i = 0; i < 24; ++i) {
        int cu = __builtin_amdgcn_readfirstlane(wv * 24 + i);   // wave-uniform channel
        const float* xc = x + ((long)(b * CINC + cu)) * HW;

        float xv[9];
        #pragma unroll
        for (int dy = 0; dy < 3; ++dy) {
            int yy = gy + dy - 1;
            bool yok = (unsigned)yy < (unsigned)HGT;
            const float* rp = xc + yy * WID;
            #pragma unroll
            for (int dx = 0; dx < 3; ++dx) {
                int xx = gx + dx - 1;
                xv[dy*3+dx] = (yok && (unsigned)xx < (unsigned)WID) ? rp[xx] : 0.f;
            }
        }
        int c1a = cu * 2;
        float wa0 = w1f[c1a*3+0], wa1 = w1f[c1a*3+1], wa2 = w1f[c1a*3+2], ba = b1f[c1a];
        float wb0 = w1f[c1a*3+3], wb1 = w1f[c1a*3+4], wb2 = w1f[c1a*3+5], bbv = b1f[c1a+1];

        // conv2 zero-pads the BN1 OUTPUT: out-of-range columns contribute 0, not bias
        float h1a[3], h1b[3];
        #pragma unroll
        for (int dx = 0; dx < 3; ++dx) {
            h1a[dx] = fmaf(wa0, xv[dx], fmaf(wa1, xv[3+dx], fmaf(wa2, xv[6+dx], ba)));
            h1b[dx] = fmaf(wb0, xv[dx], fmaf(wb1, xv[3+dx], fmaf(wb2, xv[6+dx], bbv)));
        }
        if (gx == 0)       { h1a[0] = 0.f; h1b[0] = 0.f; }
        if (gx == WID - 1) { h1a[2] = 0.f; h1b[2] = 0.f; }

        int c2b = cu * 4;
        f16x4 uv;
        #pragma unroll
        for (int jj = 0; jj < 4; ++jj) {
            float p0 = (jj < 2) ? h1a[0] : h1b[0];
            float p1 = (jj < 2) ? h1a[1] : h1b[1];
            float p2 = (jj < 2) ? h1a[2] : h1b[2];
            float w20 = w2f[(c2b+jj)*3+0], w21 = w2f[(c2b+jj)*3+1], w22 = w2f[(c2b+jj)*3+2];
            float tv = fmaf(w20, p0, fmaf(w21, p1, fmaf(w22, p2, b2f[c2b+jj])));
            tv = fminf(fmaxf(tv, 0.f), 6.f);
            uv[jj] = (_Float16)tv;
        }
        *(f16x4*)(&u_lds[pos][4 * cu]) = uv;
    }
    __syncthreads();

    // phase 2: MFMA GEMM  h[96][16pos] = Wp[96][384] * u[384][16pos]
    int lane = t & 63;
    int col = lane & 15, g = lane >> 4;
    f32x4 acc[6];
    #pragma unroll
    for (int mt = 0; mt < 6; ++mt) acc[mt] = (f32x4){0.f, 0.f, 0.f, 0.f};

    const _Float16* wp = (const _Float16*)((const char*)ws + WS_WP_BYTES);
    const _Float16* urow = &u_lds[wv * 16 + col][0];

    #pragma unroll
    for (int ks = 0; ks < 12; ++ks) {
        f16x8 bfrag = *(const f16x8*)(urow + ks * 32 + 8 * g);
        #pragma unroll
        for (int mt = 0; mt < 6; ++mt) {
            f16x8 afrag = *(const f16x8*)(wp + (mt*16 + col) * C2N + ks * 32 + 8 * g);
            acc[mt] = __builtin_amdgcn_mfma_f32_16x16x32_f16(afrag, bfrag, acc[mt], 0, 0, 0);
        }
    }
    __syncthreads();   // all u reads complete before aliasing LDS with h

    // phase 3: bn3 -> stage h (fp32) in LDS
    float* h_s = (float*)&u_lds[0][0];   // [96][64]
    const float* s3  = ws + WS_S3;
    const float* b3f = ws + WS_B3;
    int p = wv * 16 + col;
    #pragma unroll
    for (int mt = 0; mt < 6; ++mt) {
        #pragma unroll
        for (int r = 0; r < 4; ++r) {
            int m = mt * 16 + g * 4 + r;
            h_s[m * 64 + p] = fmaf(acc[mt][r], s3[m], b3f[m]);
        }
    }
    __syncthreads();

    // phase 4: gates + shuffle(48) + residual, direct to out
    long xbase = (long)b * CINC * HW + (long)gy * WID + gx;   // gy,gx from lane=pos
    #pragma unroll 4
    for (int i = 0; i < 24; ++i) {
        int o = wv * 24 + i;
        int c = (o % 48) * 2 + (o / 48);    // shuffle(48) folded
        int cn = (c + 1) % CINC;            // channel roll
        float av = a1b1[b * 192 + c];
        float bv = a1b1[b * 192 + 96 + c];
        float hv = h_s[c  * 64 + pos];
        float h2 = h_s[cn * 64 + pos];
        float xr = x[xbase + (long)o * HW];
        out[xbase + (long)o * HW] = fmaf(hv, av, fmaf(h2, bv, xr));
    }
}

extern "C" void kernel_launch(void* const* d_in, const int* in_sizes, int n_in,
                              void* d_out, int out_size, void* d_ws, size_t ws_size,
                              hipStream_t stream)
{
    const float* x    = (const float*)d_in[0];
    const float* wdw1 = (const float*)d_in[1];
    const float* g1   = (const float*)d_in[2];
    const float* b1   = (const float*)d_in[3];
    const float* m1   = (const float*)d_in[4];
    const float* v1   = (const float*)d_in[5];
    const float* wdw2 = (const float*)d_in[6];
    const float* g2   = (const float*)d_in[7];
    const float* b2   = (const float*)d_in[8];
    const float* m2   = (const float*)d_in[9];
    const float* v2   = (const float*)d_in[10];
    const float* wpw  = (const float*)d_in[11];
    const float* g3   = (const float*)d_in[12];
    const float* b3   = (const float*)d_in[13];
    const float* m3   = (const float*)d_in[14];
    const float* v3   = (const float*)d_in[15];
    const float* fc1w = (const float*)d_in[16];
    const float* fc1b = (const float*)d_in[17];
    const float* fc2w = (const float*)d_in[18];
    const float* fc2b = (const float*)d_in[19];

    float* ws   = (float*)d_ws;
    float* S    = ws + WS_S;
    float* a1b1 = ws + WS_A1B1;
    float* out  = (float*)d_out;

    hipMemsetAsync(S, 0, 6144 * sizeof(float), stream);
    k_prep<<<dim3(1), dim3(256), 0, stream>>>(
        wdw1, g1, b1, m1, v1, wdw2, g2, b2, m2, v2,
        wpw, g3, b3, m3, v3, ws);
    k_sums<<<dim3(BATCH * CINC), dim3(256), 0, stream>>>(x, ws, S);
    k_fc<<<dim3(1), dim3(384), 0, stream>>>(S, ws, wpw, fc1w, fc1b, fc2w, fc2b, a1b1);
    k_main2<<<dim3(BATCH * 196), dim3(256), 0, stream>>>(x, ws, a1b1, out);
}

// Round 5
// 289.180 us; speedup vs baseline: 1.9115x; 1.9115x over previous
//
#include <hip/hip_runtime.h>
#include <hip/hip_bf16.h>

#define BATCH 16
#define CINC 96
#define HGT 112
#define WID 112
#define HW 12544          // 112*112
#define C1N 192
#define C2N 384
#define EPSV 1e-5f

typedef _Float16 f16x8 __attribute__((ext_vector_type(8)));
typedef _Float16 f16x4 __attribute__((ext_vector_type(4)));
typedef float    f32x4 __attribute__((ext_vector_type(4)));

// d_ws layout (float offsets unless noted). Total ~118 KB.
#define WS_S      0        // 16*384 f32 u-sums (zeroed each launch)
#define WS_A1B1   6144     // 16*192 f32
#define WS_W1F    9216     // 192*3
#define WS_B1F    9792     // 192
#define WS_W2F    9984     // 384*3
#define WS_B2F    11136    // 384
#define WS_S3     11520    // 96
#define WS_B3     11616    // 96
#define WS_WP_BYTES (11712*4)   // f16 Wp[96][384] (shuffle folded)

// ---------------- prep: fold BN into weights, permute+cast pw weights ----------
// gridded: 40 blocks x 256 threads, grid-stride loops
__global__ void k_prep(const float* __restrict__ wdw1, const float* __restrict__ g1,
                       const float* __restrict__ bb1, const float* __restrict__ m1,
                       const float* __restrict__ v1,
                       const float* __restrict__ wdw2, const float* __restrict__ g2,
                       const float* __restrict__ bb2, const float* __restrict__ m2,
                       const float* __restrict__ v2,
                       const float* __restrict__ wpw, const float* __restrict__ g3,
                       const float* __restrict__ bb3, const float* __restrict__ m3,
                       const float* __restrict__ v3,
                       float* ws)
{
    int t = blockIdx.x * blockDim.x + threadIdx.x;
    int stride = gridDim.x * blockDim.x;
    float* w1f = ws + WS_W1F; float* b1f = ws + WS_B1F;
    float* w2f = ws + WS_W2F; float* b2f = ws + WS_B2F;
    float* s3  = ws + WS_S3;  float* b3f = ws + WS_B3;
    _Float16* wp = (_Float16*)((char*)ws + WS_WP_BYTES);

    for (int c = t; c < C1N; c += stride) {
        float s = g1[c] / sqrtf(v1[c] + EPSV);
        w1f[c*3+0] = wdw1[c*3+0] * s;
        w1f[c*3+1] = wdw1[c*3+1] * s;
        w1f[c*3+2] = wdw1[c*3+2] * s;
        b1f[c] = bb1[c] - m1[c] * s;
    }
    for (int c = t; c < C2N; c += stride) {
        float s = g2[c] / sqrtf(v2[c] + EPSV);
        w2f[c*3+0] = wdw2[c*3+0] * s;
        w2f[c*3+1] = wdw2[c*3+1] * s;
        w2f[c*3+2] = wdw2[c*3+2] * s;
        b2f[c] = bb2[c] - m2[c] * s;
    }
    for (int c = t; c < CINC; c += stride) {
        float s = g3[c] / sqrtf(v3[c] + EPSV);
        s3[c] = s; b3f[c] = bb3[c] - m3[c] * s;
    }
    // Wp[m][k] = w_pw[m][(k%64)*6 + k/64]  (folds channel shuffle groups=6)
    for (int idx = t; idx < CINC * C2N; idx += stride) {
        int m = idx / C2N, k = idx - m * C2N;
        int o = (k & 63) * 6 + (k >> 6);
        wp[idx] = (_Float16)wpw[m * C2N + o];
    }
}

// ---------------- pass A: per-channel u sums, all fp32 (feeds the mean path) --
// one block per (b, cin); accumulates S[b][4c..4c+3] = sum over positions of u
__global__ __launch_bounds__(256) void k_sums(const float* __restrict__ x,
                                              const float* __restrict__ ws,
                                              float* __restrict__ S)
{
    int b = blockIdx.x / CINC;
    int c = blockIdx.x - b * CINC;
    const float* w1f = ws + WS_W1F; const float* b1f = ws + WS_B1F;
    const float* w2f = ws + WS_W2F; const float* b2f = ws + WS_B2F;
    const float* xc = x + ((long)(b * CINC + c)) * HW;

    int c1a = c * 2;
    float wa0 = w1f[c1a*3+0], wa1 = w1f[c1a*3+1], wa2 = w1f[c1a*3+2], ba = b1f[c1a];
    float wb0 = w1f[c1a*3+3], wb1 = w1f[c1a*3+4], wb2 = w1f[c1a*3+5], bbv = b1f[c1a+1];
    int c2b = c * 4;
    float w2t[12], b2t[4];
    #pragma unroll
    for (int j = 0; j < 4; ++j) {
        w2t[j*3+0] = w2f[(c2b+j)*3+0];
        w2t[j*3+1] = w2f[(c2b+j)*3+1];
        w2t[j*3+2] = w2f[(c2b+j)*3+2];
        b2t[j] = b2f[c2b+j];
    }

    float acc[4] = {0.f, 0.f, 0.f, 0.f};
    for (int pos = threadIdx.x; pos < HW; pos += 256) {
        int y = pos / WID, xx = pos - y * WID;
        float xv[9];
        #pragma unroll
        for (int dy = 0; dy < 3; ++dy) {
            int yy = y + dy - 1;
            bool yok = (unsigned)yy < (unsigned)HGT;
            const float* rp = xc + yy * WID;
            #pragma unroll
            for (int dx = 0; dx < 3; ++dx) {
                int x2 = xx + dx - 1;
                xv[dy*3+dx] = (yok && (unsigned)x2 < (unsigned)WID) ? rp[x2] : 0.f;
            }
        }
        // conv2's W-padding zero-pads the BN1 OUTPUT -> out-of-range columns are 0.
        float h1a[3], h1b[3];
        #pragma unroll
        for (int dx = 0; dx < 3; ++dx) {
            h1a[dx] = fmaf(wa0, xv[dx], fmaf(wa1, xv[3+dx], fmaf(wa2, xv[6+dx], ba)));
            h1b[dx] = fmaf(wb0, xv[dx], fmaf(wb1, xv[3+dx], fmaf(wb2, xv[6+dx], bbv)));
        }
        if (xx == 0)       { h1a[0] = 0.f; h1b[0] = 0.f; }
        if (xx == WID - 1) { h1a[2] = 0.f; h1b[2] = 0.f; }
        #pragma unroll
        for (int j = 0; j < 4; ++j) {
            float p0 = (j < 2) ? h1a[0] : h1b[0];
            float p1 = (j < 2) ? h1a[1] : h1b[1];
            float p2 = (j < 2) ? h1a[2] : h1b[2];
            float tv = fmaf(w2t[j*3+0], p0, fmaf(w2t[j*3+1], p1, fmaf(w2t[j*3+2], p2, b2t[j])));
            acc[j] += fminf(fmaxf(tv, 0.f), 6.f);
        }
    }
    // wave reduce (64 lanes) then one atomic per wave per channel
    #pragma unroll
    for (int j = 0; j < 4; ++j) {
        float sv = acc[j];
        sv += __shfl_xor(sv, 1);
        sv += __shfl_xor(sv, 2);
        sv += __shfl_xor(sv, 4);
        sv += __shfl_xor(sv, 8);
        sv += __shfl_xor(sv, 16);
        sv += __shfl_xor(sv, 32);
        if ((threadIdx.x & 63) == 0) atomicAdd(&S[b * C2N + c2b + j], sv);
    }
}

// ---------------- gates: mean (S x Wp) -> MLP -> a1,b1. 16 blocks, one per batch
__global__ __launch_bounds__(384) void k_gates(const float* __restrict__ S,
                                               const float* __restrict__ ws,
                                               const float* __restrict__ wpw,
                                               const float* __restrict__ fc1w,
                                               const float* __restrict__ fc1b,
                                               const float* __restrict__ fc2w,
                                               const float* __restrict__ fc2b,
                                               float* __restrict__ a1b1)
{
    __shared__ float Ss[C2N];       // u-sums, shuffle-inverted on read
    __shared__ float mean_s[CINC];
    __shared__ float mid[24];
    int b = blockIdx.x;
    int t = threadIdx.x;            // 384 = 6 waves
    int wvi = t >> 6, lane = t & 63;

    if (t < C2N) Ss[t] = S[b * C2N + t];
    __syncthreads();

    const float* s3 = ws + WS_S3; const float* b3f = ws + WS_B3;
    // wave wvi handles m = wvi, wvi+6, ...: lane l sums 6 coalesced strips of row m
    for (int m = wvi; m < CINC; m += 6) {
        float p = 0.f;
        #pragma unroll
        for (int j = 0; j < 6; ++j) {
            int o = lane + 64 * j;                 // permuted index (coalesced read)
            int k = (o % 6) * 64 + o / 6;          // inverse shuffle into Ss
            p = fmaf(wpw[m * C2N + o], Ss[k], p);
        }
        p += __shfl_xor(p, 1);
        p += __shfl_xor(p, 2);
        p += __shfl_xor(p, 4);
        p += __shfl_xor(p, 8);
        p += __shfl_xor(p, 16);
        p += __shfl_xor(p, 32);
        if (lane == 0) mean_s[m] = fmaf(s3[m], p * (1.0f / 12544.0f), b3f[m]);
    }
    __syncthreads();

    if (t < 24) {
        float d = fc1b[t];
        #pragma unroll 4
        for (int c = 0; c < CINC; ++c) d = fmaf(fc1w[t * CINC + c], mean_s[c], d);
        mid[t] = fmaxf(d, 0.f);
    }
    __syncthreads();

    if (t < 192) {
        float d = fc2b[t];
        #pragma unroll
        for (int j = 0; j < 24; ++j) d = fmaf(fc2w[t * 24 + j], mid[j], d);
        float y = fminf(fmaxf(d + 3.f, 0.f), 6.f) * (1.f / 6.f);
        y = (y - 0.5f) * 4.f;
        a1b1[b * 192 + t] = (t < CINC) ? (y + 1.f) : y;
    }
}

// ---------------- pass B: u (fp16 LDS) -> MFMA GEMM -> bn3 -> gates+shuffle+x --
// tile = 4 rows x 16 cols (64 positions), 256 threads = 4 waves; h stays on-chip
__global__ __launch_bounds__(256) void k_main2(const float* __restrict__ x,
                                               const float* __restrict__ ws,
                                               const float* __restrict__ a1b1,
                                               float* __restrict__ out)
{
    __shared__ __align__(16) _Float16 u_lds[64][392];   // 50176 B; h_s aliases this
    int t   = threadIdx.x;
    int bid = blockIdx.x;
    int b    = bid / 196;
    int tile = bid - b * 196;
    int y0 = (tile / 7) * 4;
    int x0 = (tile % 7) * 16;

    const float* w1f = ws + WS_W1F; const float* b1f = ws + WS_B1F;
    const float* w2f = ws + WS_W2F; const float* b2f = ws + WS_B2F;

    int pos = t & 63, wv = t >> 6;
    int py = pos >> 4, px = pos & 15;
    int gy = y0 + py, gx = x0 + px;

    // phase 1: compute u (384 ch) for the 64 positions into LDS (fp16)
    #pragma unroll 2
    for (int i = 0; i < 24; ++i) {
        int cu = __builtin_amdgcn_readfirstlane(wv * 24 + i);   // wave-uniform channel
        const float* xc = x + ((long)(b * CINC + cu)) * HW;

        float xv[9];
        #pragma unroll
        for (int dy = 0; dy < 3; ++dy) {
            int yy = gy + dy - 1;
            bool yok = (unsigned)yy < (unsigned)HGT;
            const float* rp = xc + yy * WID;
            #pragma unroll
            for (int dx = 0; dx < 3; ++dx) {
                int xx = gx + dx - 1;
                xv[dy*3+dx] = (yok && (unsigned)xx < (unsigned)WID) ? rp[xx] : 0.f;
            }
        }
        int c1a = cu * 2;
        float wa0 = w1f[c1a*3+0], wa1 = w1f[c1a*3+1], wa2 = w1f[c1a*3+2], ba = b1f[c1a];
        float wb0 = w1f[c1a*3+3], wb1 = w1f[c1a*3+4], wb2 = w1f[c1a*3+5], bbv = b1f[c1a+1];

        // conv2 zero-pads the BN1 OUTPUT: out-of-range columns contribute 0, not bias
        float h1a[3], h1b[3];
        #pragma unroll
        for (int dx = 0; dx < 3; ++dx) {
            h1a[dx] = fmaf(wa0, xv[dx], fmaf(wa1, xv[3+dx], fmaf(wa2, xv[6+dx], ba)));
            h1b[dx] = fmaf(wb0, xv[dx], fmaf(wb1, xv[3+dx], fmaf(wb2, xv[6+dx], bbv)));
        }
        if (gx == 0)       { h1a[0] = 0.f; h1b[0] = 0.f; }
        if (gx == WID - 1) { h1a[2] = 0.f; h1b[2] = 0.f; }

        int c2b = cu * 4;
        f16x4 uv;
        #pragma unroll
        for (int jj = 0; jj < 4; ++jj) {
            float p0 = (jj < 2) ? h1a[0] : h1b[0];
            float p1 = (jj < 2) ? h1a[1] : h1b[1];
            float p2 = (jj < 2) ? h1a[2] : h1b[2];
            float w20 = w2f[(c2b+jj)*3+0], w21 = w2f[(c2b+jj)*3+1], w22 = w2f[(c2b+jj)*3+2];
            float tv = fmaf(w20, p0, fmaf(w21, p1, fmaf(w22, p2, b2f[c2b+jj])));
            tv = fminf(fmaxf(tv, 0.f), 6.f);
            uv[jj] = (_Float16)tv;
        }
        *(f16x4*)(&u_lds[pos][4 * cu]) = uv;
    }
    __syncthreads();

    // phase 2: MFMA GEMM  h[96][16pos] = Wp[96][384] * u[384][16pos]
    int lane = t & 63;
    int col = lane & 15, g = lane >> 4;
    f32x4 acc[6];
    #pragma unroll
    for (int mt = 0; mt < 6; ++mt) acc[mt] = (f32x4){0.f, 0.f, 0.f, 0.f};

    const _Float16* wp = (const _Float16*)((const char*)ws + WS_WP_BYTES);
    const _Float16* urow = &u_lds[wv * 16 + col][0];

    #pragma unroll
    for (int ks = 0; ks < 12; ++ks) {
        f16x8 bfrag = *(const f16x8*)(urow + ks * 32 + 8 * g);
        #pragma unroll
        for (int mt = 0; mt < 6; ++mt) {
            f16x8 afrag = *(const f16x8*)(wp + (mt*16 + col) * C2N + ks * 32 + 8 * g);
            acc[mt] = __builtin_amdgcn_mfma_f32_16x16x32_f16(afrag, bfrag, acc[mt], 0, 0, 0);
        }
    }
    __syncthreads();   // all u reads complete before aliasing LDS with h

    // phase 3: bn3 -> stage h (fp32) in LDS
    float* h_s = (float*)&u_lds[0][0];   // [96][64]
    const float* s3  = ws + WS_S3;
    const float* b3f = ws + WS_B3;
    int p = wv * 16 + col;
    #pragma unroll
    for (int mt = 0; mt < 6; ++mt) {
        #pragma unroll
        for (int r = 0; r < 4; ++r) {
            int m = mt * 16 + g * 4 + r;
            h_s[m * 64 + p] = fmaf(acc[mt][r], s3[m], b3f[m]);
        }
    }
    __syncthreads();

    // phase 4: gates + shuffle(48) + residual, direct to out
    long xbase = (long)b * CINC * HW + (long)gy * WID + gx;   // gy,gx from lane=pos
    #pragma unroll 4
    for (int i = 0; i < 24; ++i) {
        int o = wv * 24 + i;
        int c = (o % 48) * 2 + (o / 48);    // shuffle(48) folded
        int cn = (c + 1) % CINC;            // channel roll
        float av = a1b1[b * 192 + c];
        float bv = a1b1[b * 192 + 96 + c];
        float hv = h_s[c  * 64 + pos];
        float h2 = h_s[cn * 64 + pos];
        float xr = x[xbase + (long)o * HW];
        out[xbase + (long)o * HW] = fmaf(hv, av, fmaf(h2, bv, xr));
    }
}

extern "C" void kernel_launch(void* const* d_in, const int* in_sizes, int n_in,
                              void* d_out, int out_size, void* d_ws, size_t ws_size,
                              hipStream_t stream)
{
    const float* x    = (const float*)d_in[0];
    const float* wdw1 = (const float*)d_in[1];
    const float* g1   = (const float*)d_in[2];
    const float* b1   = (const float*)d_in[3];
    const float* m1   = (const float*)d_in[4];
    const float* v1   = (const float*)d_in[5];
    const float* wdw2 = (const float*)d_in[6];
    const float* g2   = (const float*)d_in[7];
    const float* b2   = (const float*)d_in[8];
    const float* m2   = (const float*)d_in[9];
    const float* v2   = (const float*)d_in[10];
    const float* wpw  = (const float*)d_in[11];
    const float* g3   = (const float*)d_in[12];
    const float* b3   = (const float*)d_in[13];
    const float* m3   = (const float*)d_in[14];
    const float* v3   = (const float*)d_in[15];
    const float* fc1w = (const float*)d_in[16];
    const float* fc1b = (const float*)d_in[17];
    const float* fc2w = (const float*)d_in[18];
    const float* fc2b = (const float*)d_in[19];

    float* ws   = (float*)d_ws;
    float* S    = ws + WS_S;
    float* a1b1 = ws + WS_A1B1;
    float* out  = (float*)d_out;

    hipMemsetAsync(S, 0, 6144 * sizeof(float), stream);
    k_prep<<<dim3(40), dim3(256), 0, stream>>>(
        wdw1, g1, b1, m1, v1, wdw2, g2, b2, m2, v2,
        wpw, g3, b3, m3, v3, ws);
    k_sums<<<dim3(BATCH * CINC), dim3(256), 0, stream>>>(x, ws, S);
    k_gates<<<dim3(BATCH), dim3(384), 0, stream>>>(S, ws, wpw, fc1w, fc1b, fc2w, fc2b, a1b1);
    k_main2<<<dim3(BATCH * 196), dim3(256), 0, stream>>>(x, ws, a1b1, out);
}

// Round 6
// 225.538 us; speedup vs baseline: 2.4508x; 1.2822x over previous
//
#include <hip/hip_runtime.h>
#include <hip/hip_bf16.h>

#define BATCH 16
#define CINC 96
#define HGT 112
#define WID 112
#define HW 12544          // 112*112
#define C1N 192
#define C2N 384
#define EPSV 1e-5f

typedef _Float16 f16x8 __attribute__((ext_vector_type(8)));
typedef _Float16 f16x4 __attribute__((ext_vector_type(4)));
typedef float    f32x4 __attribute__((ext_vector_type(4)));

// d_ws layout (float offsets unless noted)
#define WS_S      0        // 16*96 f32 h-sums (zeroed each launch)
#define WS_A1B1   1536     // 16*192 f32
#define WS_W1F    4608     // 192*3
#define WS_B1F    5184     // 192
#define WS_W2F    5376     // 384*3
#define WS_B2F    6528     // 384
#define WS_S3     6912     // 96
#define WS_B3     7008     // 96
#define WS_WP_BYTES (7104*4)                   // f16 Wp[96][384] (shuffle folded)
#define WS_H_BYTES  (WS_WP_BYTES + CINC*C2N*2) // f16 h[16][96][12544] = 38.5 MB

// ---------------- prep: fold BN into weights, permute+cast pw weights ----------
__global__ void k_prep(const float* __restrict__ wdw1, const float* __restrict__ g1,
                       const float* __restrict__ bb1, const float* __restrict__ m1,
                       const float* __restrict__ v1,
                       const float* __restrict__ wdw2, const float* __restrict__ g2,
                       const float* __restrict__ bb2, const float* __restrict__ m2,
                       const float* __restrict__ v2,
                       const float* __restrict__ wpw, const float* __restrict__ g3,
                       const float* __restrict__ bb3, const float* __restrict__ m3,
                       const float* __restrict__ v3,
                       float* ws)
{
    int t = blockIdx.x * blockDim.x + threadIdx.x;
    int stride = gridDim.x * blockDim.x;
    float* w1f = ws + WS_W1F; float* b1f = ws + WS_B1F;
    float* w2f = ws + WS_W2F; float* b2f = ws + WS_B2F;
    float* s3  = ws + WS_S3;  float* b3f = ws + WS_B3;
    _Float16* wp = (_Float16*)((char*)ws + WS_WP_BYTES);

    for (int c = t; c < C1N; c += stride) {
        float s = g1[c] / sqrtf(v1[c] + EPSV);
        w1f[c*3+0] = wdw1[c*3+0] * s;
        w1f[c*3+1] = wdw1[c*3+1] * s;
        w1f[c*3+2] = wdw1[c*3+2] * s;
        b1f[c] = bb1[c] - m1[c] * s;
    }
    for (int c = t; c < C2N; c += stride) {
        float s = g2[c] / sqrtf(v2[c] + EPSV);
        w2f[c*3+0] = wdw2[c*3+0] * s;
        w2f[c*3+1] = wdw2[c*3+1] * s;
        w2f[c*3+2] = wdw2[c*3+2] * s;
        b2f[c] = bb2[c] - m2[c] * s;
    }
    for (int c = t; c < CINC; c += stride) {
        float s = g3[c] / sqrtf(v3[c] + EPSV);
        s3[c] = s; b3f[c] = bb3[c] - m3[c] * s;
    }
    // Wp[m][k] = w_pw[m][(k%64)*6 + k/64]  (folds channel shuffle groups=6)
    for (int idx = t; idx < CINC * C2N; idx += stride) {
        int m = idx / C2N, k = idx - m * C2N;
        int o = (k & 63) * 6 + (k >> 6);
        wp[idx] = (_Float16)wpw[m * C2N + o];
    }
}

// ---------------- main: dw1+dw2+relu6 -> (shuffled) pw MFMA -> bn3 -> h(fp16)+sums
// tile = 4 rows x 16 cols (64 positions), 256 threads = 4 waves
// K split in two halves of 192 to keep LDS at 25.6 KB -> 6 blocks/CU
__global__ __launch_bounds__(256, 6) void k_main3(const float* __restrict__ x,
                                                  const float* __restrict__ ws,
                                                  float* __restrict__ sums,
                                                  _Float16* __restrict__ h_out)
{
    __shared__ __align__(16) _Float16 u_lds[64][200];   // 192 + 8 pad = 25.6 KB
    __shared__ float ssum[CINC];

    int t   = threadIdx.x;
    int bid = blockIdx.x;
    int b    = bid / 196;
    int tile = bid - b * 196;
    int y0 = (tile / 7) * 4;
    int x0 = (tile % 7) * 16;

    const float* w1f = ws + WS_W1F; const float* b1f = ws + WS_B1F;
    const float* w2f = ws + WS_W2F; const float* b2f = ws + WS_B2F;

    if (t < CINC) ssum[t] = 0.f;

    int pos = t & 63, wv = t >> 6;
    int py = pos >> 4, px = pos & 15;
    int gy = y0 + py, gx = x0 + px;
    int lane = t & 63;
    int col = lane & 15, g = lane >> 4;

    f32x4 acc[6];
    #pragma unroll
    for (int mt = 0; mt < 6; ++mt) acc[mt] = (f32x4){0.f, 0.f, 0.f, 0.f};

    const _Float16* wp = (const _Float16*)((const char*)ws + WS_WP_BYTES);
    const _Float16* urow = &u_lds[wv * 16 + col][0];

    #pragma unroll
    for (int half = 0; half < 2; ++half) {
        // phase 1: compute u for 48 dw-channels (192 k) into LDS (fp16)
        #pragma unroll 2
        for (int i = 0; i < 12; ++i) {
            int cu = __builtin_amdgcn_readfirstlane(half * 48 + wv * 12 + i);
            const float* xc = x + ((long)(b * CINC + cu)) * HW;

            float xv[9];
            #pragma unroll
            for (int dy = 0; dy < 3; ++dy) {
                int yy = gy + dy - 1;
                bool yok = (unsigned)yy < (unsigned)HGT;
                const float* rp = xc + yy * WID;
                #pragma unroll
                for (int dx = 0; dx < 3; ++dx) {
                    int xx = gx + dx - 1;
                    xv[dy*3+dx] = (yok && (unsigned)xx < (unsigned)WID) ? rp[xx] : 0.f;
                }
            }
            int c1a = cu * 2;
            float wa0 = w1f[c1a*3+0], wa1 = w1f[c1a*3+1], wa2 = w1f[c1a*3+2], ba = b1f[c1a];
            float wb0 = w1f[c1a*3+3], wb1 = w1f[c1a*3+4], wb2 = w1f[c1a*3+5], bbv = b1f[c1a+1];

            // conv2 zero-pads the BN1 OUTPUT: out-of-range columns contribute 0
            float h1a[3], h1b[3];
            #pragma unroll
            for (int dx = 0; dx < 3; ++dx) {
                h1a[dx] = fmaf(wa0, xv[dx], fmaf(wa1, xv[3+dx], fmaf(wa2, xv[6+dx], ba)));
                h1b[dx] = fmaf(wb0, xv[dx], fmaf(wb1, xv[3+dx], fmaf(wb2, xv[6+dx], bbv)));
            }
            if (gx == 0)       { h1a[0] = 0.f; h1b[0] = 0.f; }
            if (gx == WID - 1) { h1a[2] = 0.f; h1b[2] = 0.f; }

            int c2b = cu * 4;
            f16x4 uv;
            #pragma unroll
            for (int jj = 0; jj < 4; ++jj) {
                float p0 = (jj < 2) ? h1a[0] : h1b[0];
                float p1 = (jj < 2) ? h1a[1] : h1b[1];
                float p2 = (jj < 2) ? h1a[2] : h1b[2];
                float w20 = w2f[(c2b+jj)*3+0], w21 = w2f[(c2b+jj)*3+1], w22 = w2f[(c2b+jj)*3+2];
                float tv = fmaf(w20, p0, fmaf(w21, p1, fmaf(w22, p2, b2f[c2b+jj])));
                tv = fminf(fmaxf(tv, 0.f), 6.f);
                uv[jj] = (_Float16)tv;
            }
            *(f16x4*)(&u_lds[pos][(wv * 12 + i) * 4]) = uv;
        }
        __syncthreads();

        // phase 2: partial MFMA GEMM over this half's 192 k
        #pragma unroll
        for (int ks = 0; ks < 6; ++ks) {
            f16x8 bfrag = *(const f16x8*)(urow + ks * 32 + 8 * g);
            #pragma unroll
            for (int mt = 0; mt < 6; ++mt) {
                f16x8 afrag = *(const f16x8*)(wp + (mt*16 + col) * C2N + half * 192 + ks * 32 + 8 * g);
                acc[mt] = __builtin_amdgcn_mfma_f32_16x16x32_f16(afrag, bfrag, acc[mt], 0, 0, 0);
            }
        }
        __syncthreads();   // reads done before next half overwrites LDS
    }

    // epilogue: bn3 -> store h (fp16) -> per-channel sums
    const float* s3  = ws + WS_S3;
    const float* b3f = ws + WS_B3;
    int gy2 = y0 + wv, gx2 = x0 + col;
    #pragma unroll
    for (int mt = 0; mt < 6; ++mt) {
        #pragma unroll
        for (int r = 0; r < 4; ++r) {
            int m = mt * 16 + g * 4 + r;
            float hv = fmaf(acc[mt][r], s3[m], b3f[m]);
            h_out[((long)(b * CINC + m)) * HW + gy2 * WID + gx2] = (_Float16)hv;
            float sv = hv;
            sv += __shfl_xor(sv, 1);
            sv += __shfl_xor(sv, 2);
            sv += __shfl_xor(sv, 4);
            sv += __shfl_xor(sv, 8);
            if (col == 0) atomicAdd(&ssum[m], sv);
        }
    }
    __syncthreads();
    if (t < CINC) atomicAdd(&sums[b * CINC + t], ssum[t]);
}

// ---------------- gates: mean(h) -> fc1+relu -> fc2 -> hardsig -> a1,b1 -------
__global__ __launch_bounds__(192) void k_gates(const float* __restrict__ sums,
                                               const float* __restrict__ fc1w,
                                               const float* __restrict__ fc1b,
                                               const float* __restrict__ fc2w,
                                               const float* __restrict__ fc2b,
                                               float* __restrict__ a1b1)
{
    __shared__ float mean_s[CINC];
    __shared__ float mid[24];
    int b = blockIdx.x;
    int t = threadIdx.x;     // 192

    if (t < CINC) mean_s[t] = sums[b * CINC + t] * (1.0f / 12544.0f);
    __syncthreads();
    if (t < 24) {
        float d = fc1b[t];
        #pragma unroll 4
        for (int c = 0; c < CINC; ++c) d = fmaf(fc1w[t * CINC + c], mean_s[c], d);
        mid[t] = fmaxf(d, 0.f);
    }
    __syncthreads();
    {
        float d = fc2b[t];
        #pragma unroll
        for (int j = 0; j < 24; ++j) d = fmaf(fc2w[t * 24 + j], mid[j], d);
        float y = fminf(fmaxf(d + 3.f, 0.f), 6.f) * (1.f / 6.f);
        y = (y - 0.5f) * 4.f;
        a1b1[b * 192 + t] = (t < CINC) ? (y + 1.f) : y;
    }
}

// ---------------- final: h*a1 + roll(h)*b1, shuffle(48), + x (pure streaming) --
__global__ __launch_bounds__(256) void k_final(const _Float16* __restrict__ h,
                                               const float* __restrict__ xin,
                                               const float* __restrict__ a1b1,
                                               float* __restrict__ out)
{
    int q = blockIdx.x * 256 + threadIdx.x;      // 4,816,896 quads total (exact)
    int pos4 = q % 3136;
    int bo = q / 3136;
    int o = bo % CINC, b = bo / CINC;
    int c = (o % 48) * 2 + (o / 48);             // shuffle(48) folded
    int cn = (c + 1) % CINC;                      // channel roll

    float av = a1b1[b * 192 + c];
    float bv = a1b1[b * 192 + 96 + c];

    long hb = (long)b * CINC * HW;
    f16x4 hv4 = *(const f16x4*)(h + hb + (long)c  * HW + pos4 * 4);
    f16x4 h2v = *(const f16x4*)(h + hb + (long)cn * HW + pos4 * 4);

    long xo = ((long)(b * CINC + o)) * HW + pos4 * 4;
    f32x4 xv = *(const f32x4*)(xin + xo);
    f32x4 r;
    #pragma unroll
    for (int j = 0; j < 4; ++j)
        r[j] = fmaf((float)hv4[j], av, fmaf((float)h2v[j], bv, xv[j]));
    *(f32x4*)(out + xo) = r;
}

extern "C" void kernel_launch(void* const* d_in, const int* in_sizes, int n_in,
                              void* d_out, int out_size, void* d_ws, size_t ws_size,
                              hipStream_t stream)
{
    const float* x    = (const float*)d_in[0];
    const float* wdw1 = (const float*)d_in[1];
    const float* g1   = (const float*)d_in[2];
    const float* b1   = (const float*)d_in[3];
    const float* m1   = (const float*)d_in[4];
    const float* v1   = (const float*)d_in[5];
    const float* wdw2 = (const float*)d_in[6];
    const float* g2   = (const float*)d_in[7];
    const float* b2   = (const float*)d_in[8];
    const float* m2   = (const float*)d_in[9];
    const float* v2   = (const float*)d_in[10];
    const float* wpw  = (const float*)d_in[11];
    const float* g3   = (const float*)d_in[12];
    const float* b3   = (const float*)d_in[13];
    const float* m3   = (const float*)d_in[14];
    const float* v3   = (const float*)d_in[15];
    const float* fc1w = (const float*)d_in[16];
    const float* fc1b = (const float*)d_in[17];
    const float* fc2w = (const float*)d_in[18];
    const float* fc2b = (const float*)d_in[19];

    float* ws   = (float*)d_ws;
    float* sums = ws + WS_S;
    float* a1b1 = ws + WS_A1B1;
    _Float16* hbuf = (_Float16*)((char*)d_ws + WS_H_BYTES);
    float* out  = (float*)d_out;

    hipMemsetAsync(sums, 0, 1536 * sizeof(float), stream);
    k_prep<<<dim3(40), dim3(256), 0, stream>>>(
        wdw1, g1, b1, m1, v1, wdw2, g2, b2, m2, v2,
        wpw, g3, b3, m3, v3, ws);
    k_main3<<<dim3(BATCH * 196), dim3(256), 0, stream>>>(x, ws, sums, hbuf);
    k_gates<<<dim3(BATCH), dim3(192), 0, stream>>>(sums, fc1w, fc1b, fc2w, fc2b, a1b1);
    k_final<<<dim3(4816896 / 256), dim3(256), 0, stream>>>(hbuf, x, a1b1, out);
}

// Round 8
// 196.395 us; speedup vs baseline: 2.8145x; 1.1484x over previous
//
#include <hip/hip_runtime.h>
#include <hip/hip_bf16.h>

#define BATCH 16
#define CINC 96
#define HGT 112
#define WID 112
#define HW 12544          // 112*112
#define C1N 192
#define C2N 384
#define EPSV 1e-5f

typedef _Float16 f16x8 __attribute__((ext_vector_type(8)));
typedef _Float16 f16x4 __attribute__((ext_vector_type(4)));
typedef float    f32x4 __attribute__((ext_vector_type(4)));

// d_ws layout (float offsets unless noted)
#define WS_S      0        // 16*96 f32 h-sums (zeroed each launch)
#define WS_A1B1   1536     // 16*192 f32
#define WS_W1F    4608     // 192*3
#define WS_B1F    5184     // 192
#define WS_W2F    5376     // 384*3
#define WS_B2F    6528     // 384
#define WS_S3     6912     // 96
#define WS_B3     7008     // 96
#define WS_WPF_BYTES (7104*4)                    // f16 wpf: fragment-contiguous Wp
#define WS_H_BYTES   (WS_WPF_BYTES + CINC*C2N*2) // f16 h[16][96][12544] = 38.5 MB

// ---------------- prep: fold BN into weights; Wp -> fragment-contiguous f16 ----
// wpf[((rt*12+ks)*64 + lane)*8 + e] = Wp[rt*16+col][ks*32+g*8+e], lane=(g<<4)|col
// where Wp[m][k] = w_pw[m][(k%64)*6 + k/64]  (channel shuffle groups=6 folded)
__global__ void k_prep(const float* __restrict__ wdw1, const float* __restrict__ g1,
                       const float* __restrict__ bb1, const float* __restrict__ m1,
                       const float* __restrict__ v1,
                       const float* __restrict__ wdw2, const float* __restrict__ g2,
                       const float* __restrict__ bb2, const float* __restrict__ m2,
                       const float* __restrict__ v2,
                       const float* __restrict__ wpw, const float* __restrict__ g3,
                       const float* __restrict__ bb3, const float* __restrict__ m3,
                       const float* __restrict__ v3,
                       float* ws)
{
    int t = blockIdx.x * blockDim.x + threadIdx.x;
    int stride = gridDim.x * blockDim.x;
    float* w1f = ws + WS_W1F; float* b1f = ws + WS_B1F;
    float* w2f = ws + WS_W2F; float* b2f = ws + WS_B2F;
    float* s3  = ws + WS_S3;  float* b3f = ws + WS_B3;
    _Float16* wpf = (_Float16*)((char*)ws + WS_WPF_BYTES);

    for (int c = t; c < C1N; c += stride) {
        float s = g1[c] / sqrtf(v1[c] + EPSV);
        w1f[c*3+0] = wdw1[c*3+0] * s;
        w1f[c*3+1] = wdw1[c*3+1] * s;
        w1f[c*3+2] = wdw1[c*3+2] * s;
        b1f[c] = bb1[c] - m1[c] * s;
    }
    for (int c = t; c < C2N; c += stride) {
        float s = g2[c] / sqrtf(v2[c] + EPSV);
        w2f[c*3+0] = wdw2[c*3+0] * s;
        w2f[c*3+1] = wdw2[c*3+1] * s;
        w2f[c*3+2] = wdw2[c*3+2] * s;
        b2f[c] = bb2[c] - m2[c] * s;
    }
    for (int c = t; c < CINC; c += stride) {
        float s = g3[c] / sqrtf(v3[c] + EPSV);
        s3[c] = s; b3f[c] = bb3[c] - m3[c] * s;
    }
    for (int idx = t; idx < CINC * C2N; idx += stride) {
        int e = idx & 7;
        int r = idx >> 3;
        int lane = r & 63; r >>= 6;
        int ks = r % 12, rt = r / 12;
        int col = lane & 15, g = lane >> 4;
        int m = rt * 16 + col;
        int k = ks * 32 + g * 8 + e;
        int o = (k & 63) * 6 + (k >> 6);
        wpf[idx] = (_Float16)wpw[m * C2N + o];
    }
}

// ---------------- main: separable dw1/dw2 (shfl-shared) -> MFMA -> h(f16)+sums --
// block = 4 rows x 64 cols (256 thr, wave = one row); K in 4 chunks of 96
// col-halves: x0 = 0 (cols 0..63) and x0 = 48 (cols 48..111), overlap masked in sums
__global__ __launch_bounds__(256, 2) void k_main4(const float* __restrict__ x,
                                                  const float* __restrict__ ws,
                                                  float* __restrict__ sums,
                                                  _Float16* __restrict__ h_out)
{
    __shared__ __align__(16) _Float16 u_lds[256][104];   // 53248 B; h_s aliases this
    __shared__ float ssum[CINC];

    int t   = threadIdx.x;
    int bid = blockIdx.x;
    int logical = (bid & 7) * 112 + (bid >> 3);   // XCD-chunked (896 = 8*112)
    int b   = logical / 56;
    int rem = logical - b * 56;
    int y0  = (rem >> 1) * 4;
    int x0  = (rem & 1) * 48;

    int py = t >> 6, lane = t & 63;
    int gy = y0 + py;
    int gxg = x0 + lane;

    const float* w1f = ws + WS_W1F; const float* b1f = ws + WS_B1F;
    const float* w2f = ws + WS_W2F; const float* b2f = ws + WS_B2F;

    if (t < CINC) ssum[t] = 0.f;

    bool ymok = gy >= 1;
    bool ypok = gy + 1 < HGT;
    bool isL = (lane == 0), isR = (lane == 63);
    int  colB = isL ? (x0 - 1) : (x0 + 64);
    bool bok  = (isL | isR) && (unsigned)colB < (unsigned)WID;

    int col16 = lane & 15, g = lane >> 4;
    long xrow = (long)gy * WID;

    f32x4 acc[6][4];
    #pragma unroll
    for (int rt = 0; rt < 6; ++rt)
        #pragma unroll
        for (int ct = 0; ct < 4; ++ct) acc[rt][ct] = (f32x4){0.f, 0.f, 0.f, 0.f};

    const _Float16* wpf = (const _Float16*)((const char*)ws + WS_WPF_BYTES);
    long xb = (long)b * CINC * HW;

    for (int chunk = 0; chunk < 4; ++chunk) {
        if (chunk) __syncthreads();              // MFMA reads of prev chunk done
        // ---- gather: u for 24 dw-channels (96 k) into LDS ----
        #pragma unroll 4
        for (int i = 0; i < 24; ++i) {
            int cu = chunk * 24 + i;
            const float* xp = x + xb + (long)cu * HW + xrow + gxg;
            float xm = ymok ? xp[-WID] : 0.f;
            float xz = xp[0];
            float xq = ypok ? xp[WID] : 0.f;

            float bm = 0.f, bz = 0.f, bq = 0.f;
            if (bok) {
                const float* xbp = x + xb + (long)cu * HW + xrow + colB;
                bm = ymok ? xbp[-WID] : 0.f;
                bz = xbp[0];
                bq = ypok ? xbp[WID] : 0.f;
            }

            int c1a = cu * 2;
            float wa0 = w1f[c1a*3+0], wa1 = w1f[c1a*3+1], wa2 = w1f[c1a*3+2], ba = b1f[c1a];
            float wb0 = w1f[c1a*3+3], wb1 = w1f[c1a*3+4], wb2 = w1f[c1a*3+5], bb = b1f[c1a+1];

            // vertical 3x1 conv + BN1 (v); zero outside image handled via bok
            float va = fmaf(wa0, xm, fmaf(wa1, xz, fmaf(wa2, xq, ba)));
            float vb = fmaf(wb0, xm, fmaf(wb1, xz, fmaf(wb2, xq, bb)));
            float vba = fmaf(wa0, bm, fmaf(wa1, bz, fmaf(wa2, bq, ba)));
            float vbb = fmaf(wb0, bm, fmaf(wb1, bz, fmaf(wb2, bq, bb)));

            // horizontal neighbors via shuffle (wave = one row)
            float vla = __shfl(va, (lane + 63) & 63);
            float vlb = __shfl(vb, (lane + 63) & 63);
            float vra = __shfl(va, (lane + 1) & 63);
            float vrb = __shfl(vb, (lane + 1) & 63);
            if (isL) { vla = bok ? vba : 0.f; vlb = bok ? vbb : 0.f; }
            if (isR) { vra = bok ? vba : 0.f; vrb = bok ? vbb : 0.f; }

            int c2b = cu * 4;
            f16x4 uv;
            #pragma unroll
            for (int j = 0; j < 4; ++j) {
                float pl = (j < 2) ? vla : vlb;
                float pc = (j < 2) ? va  : vb;
                float pr = (j < 2) ? vra : vrb;
                float w20 = w2f[(c2b+j)*3+0], w21 = w2f[(c2b+j)*3+1], w22 = w2f[(c2b+j)*3+2];
                float tv = fmaf(w20, pl, fmaf(w21, pc, fmaf(w22, pr, b2f[c2b+j])));
                tv = fminf(fmaxf(tv, 0.f), 6.f);
                uv[j] = (_Float16)tv;
            }
            *(f16x4*)(&u_lds[t][i * 4]) = uv;
        }
        __syncthreads();

        // ---- MFMA: acc += Wp[:, chunk k-slice] * u ----
        #pragma unroll
        for (int ks = 0; ks < 3; ++ks) {
            int ksg = chunk * 3 + ks;
            f16x8 bfr[4];
            #pragma unroll
            for (int ct = 0; ct < 4; ++ct)
                bfr[ct] = *(const f16x8*)(&u_lds[py * 64 + ct * 16 + col16][ks * 32 + g * 8]);
            #pragma unroll
            for (int rt = 0; rt < 6; ++rt) {
                f16x8 afr = *(const f16x8*)(wpf + ((rt * 12 + ksg) * 64 + lane) * 8);
                #pragma unroll
                for (int ct = 0; ct < 4; ++ct)
                    acc[rt][ct] = __builtin_amdgcn_mfma_f32_16x16x32_f16(afr, bfr[ct], acc[rt][ct], 0, 0, 0);
            }
        }
    }
    __syncthreads();

    // ---- stage h (bn3, f16) into LDS (aliases u_lds) ----
    _Float16* h_s = &u_lds[0][0];    // [96][256]
    const float* s3  = ws + WS_S3;
    const float* b3f = ws + WS_B3;
    #pragma unroll
    for (int rt = 0; rt < 6; ++rt) {
        #pragma unroll
        for (int ct = 0; ct < 4; ++ct) {
            int p = py * 64 + ct * 16 + col16;
            #pragma unroll
            for (int r = 0; r < 4; ++r) {
                int m = rt * 16 + g * 4 + r;
                h_s[m * 256 + p] = (_Float16)fmaf(acc[rt][ct][r], s3[m], b3f[m]);
            }
        }
    }
    __syncthreads();

    // ---- coalesced full-line h stores + channel sums (overlap-masked) ----
    #pragma unroll
    for (int i = 0; i < 12; ++i) {
        int flat = i * 2048 + t * 8;           // covers 96*256 exactly
        int m = flat >> 8;
        int p = flat & 255;
        f16x8 hv = *(const f16x8*)(h_s + flat);
        int row = y0 + (p >> 6);
        int colg = x0 + (p & 63);
        *(f16x8*)(h_out + ((long)(b * CINC + m)) * HW + (long)row * WID + colg) = hv;

        float s = 0.f;
        if (!(x0 == 48 && (p & 63) < 16)) {    // overlap cols 48..63 counted by half-0
            #pragma unroll
            for (int e = 0; e < 8; ++e) s += (float)hv[e];
        }
        s += __shfl_xor(s, 1);
        s += __shfl_xor(s, 2);
        s += __shfl_xor(s, 4);
        s += __shfl_xor(s, 8);
        s += __shfl_xor(s, 16);
        if ((lane & 31) == 0) atomicAdd(&ssum[m], s);
    }
    __syncthreads();
    if (t < CINC) atomicAdd(&sums[b * CINC + t], ssum[t]);
}

// ---------------- gates: mean(h) -> fc1+relu -> fc2 -> hardsig -> a1,b1 -------
__global__ __launch_bounds__(192) void k_gates(const float* __restrict__ sums,
                                               const float* __restrict__ fc1w,
                                               const float* __restrict__ fc1b,
                                               const float* __restrict__ fc2w,
                                               const float* __restrict__ fc2b,
                                               float* __restrict__ a1b1)
{
    __shared__ float mean_s[CINC];
    __shared__ float mid[24];
    int b = blockIdx.x;
    int t = threadIdx.x;     // 192

    if (t < CINC) mean_s[t] = sums[b * CINC + t] * (1.0f / 12544.0f);
    __syncthreads();
    if (t < 24) {
        float d = fc1b[t];
        #pragma unroll 4
        for (int c = 0; c < CINC; ++c) d = fmaf(fc1w[t * CINC + c], mean_s[c], d);
        mid[t] = fmaxf(d, 0.f);
    }
    __syncthreads();
    {
        float d = fc2b[t];
        #pragma unroll
        for (int j = 0; j < 24; ++j) d = fmaf(fc2w[t * 24 + j], mid[j], d);
        float y = fminf(fmaxf(d + 3.f, 0.f), 6.f) * (1.f / 6.f);
        y = (y - 0.5f) * 4.f;
        a1b1[b * 192 + t] = (t < CINC) ? (y + 1.f) : y;
    }
}

// ---------------- final: h*a1 + roll(h)*b1, shuffle(48), + x (pure streaming) --
__global__ __launch_bounds__(256) void k_final(const _Float16* __restrict__ h,
                                               const float* __restrict__ xin,
                                               const float* __restrict__ a1b1,
                                               float* __restrict__ out)
{
    int q = blockIdx.x * 256 + threadIdx.x;      // 4,816,896 quads total (exact)
    int pos4 = q % 3136;
    int bo = q / 3136;
    int o = bo % CINC, b = bo / CINC;
    int c = (o % 48) * 2 + (o / 48);             // shuffle(48) folded
    int cn = (c + 1) % CINC;                      // channel roll

    float av = a1b1[b * 192 + c];
    float bv = a1b1[b * 192 + 96 + c];

    long hb = (long)b * CINC * HW;
    f16x4 hv4 = *(const f16x4*)(h + hb + (long)c  * HW + pos4 * 4);
    f16x4 h2v = *(const f16x4*)(h + hb + (long)cn * HW + pos4 * 4);

    long xo = ((long)(b * CINC + o)) * HW + pos4 * 4;
    f32x4 xv = *(const f32x4*)(xin + xo);
    f32x4 r;
    #pragma unroll
    for (int j = 0; j < 4; ++j)
        r[j] = fmaf((float)hv4[j], av, fmaf((float)h2v[j], bv, xv[j]));
    *(f32x4*)(out + xo) = r;
}

extern "C" void kernel_launch(void* const* d_in, const int* in_sizes, int n_in,
                              void* d_out, int out_size, void* d_ws, size_t ws_size,
                              hipStream_t stream)
{
    const float* x    = (const float*)d_in[0];
    const float* wdw1 = (const float*)d_in[1];
    const float* g1   = (const float*)d_in[2];
    const float* b1   = (const float*)d_in[3];
    const float* m1   = (const float*)d_in[4];
    const float* v1   = (const float*)d_in[5];
    const float* wdw2 = (const float*)d_in[6];
    const float* g2   = (const float*)d_in[7];
    const float* b2   = (const float*)d_in[8];
    const float* m2   = (const float*)d_in[9];
    const float* v2   = (const float*)d_in[10];
    const float* wpw  = (const float*)d_in[11];
    const float* g3   = (const float*)d_in[12];
    const float* b3   = (const float*)d_in[13];
    const float* m3   = (const float*)d_in[14];
    const float* v3   = (const float*)d_in[15];
    const float* fc1w = (const float*)d_in[16];
    const float* fc1b = (const float*)d_in[17];
    const float* fc2w = (const float*)d_in[18];
    const float* fc2b = (const float*)d_in[19];

    float* ws   = (float*)d_ws;
    float* sums = ws + WS_S;
    float* a1b1 = ws + WS_A1B1;
    _Float16* hbuf = (_Float16*)((char*)d_ws + WS_H_BYTES);
    float* out  = (float*)d_out;

    hipMemsetAsync(sums, 0, 1536 * sizeof(float), stream);
    k_prep<<<dim3(40), dim3(256), 0, stream>>>(
        wdw1, g1, b1, m1, v1, wdw2, g2, b2, m2, v2,
        wpw, g3, b3, m3, v3, ws);
    k_main4<<<dim3(896), dim3(256), 0, stream>>>(x, ws, sums, hbuf);
    k_gates<<<dim3(BATCH), dim3(192), 0, stream>>>(sums, fc1w, fc1b, fc2w, fc2b, a1b1);
    k_final<<<dim3(4816896 / 256), dim3(256), 0, stream>>>(hbuf, x, a1b1, out);
}

// Round 10
// 120.075 us; speedup vs baseline: 4.6034x; 1.6356x over previous
//
#include <hip/hip_runtime.h>
#include <hip/hip_bf16.h>

#define BATCH 16
#define CINC 96
#define HGT 112
#define WID 112
#define HW 12544          // 112*112
#define C1N 192
#define C2N 384
#define EPSV 1e-5f

typedef _Float16 f16x8 __attribute__((ext_vector_type(8)));
typedef _Float16 f16x4 __attribute__((ext_vector_type(4)));
typedef float    f32x4 __attribute__((ext_vector_type(4)));

// d_ws layout (float offsets unless noted)
#define WS_S      0        // 16*96 f32 h-sums (zeroed each launch)
#define WS_A1B1   1536     // 16*192 f32
#define WS_W1F    4608     // 192*3
#define WS_B1F    5184     // 192
#define WS_W2F    5376     // 384*3
#define WS_B2F    6528     // 384
#define WS_S3     6912     // 96
#define WS_B3     7008     // 96
#define WS_WPF_BYTES (7104*4)                    // f16 wpf[ksg][rt][lane][8] (chunk-contiguous)
#define WS_H_BYTES   (WS_WPF_BYTES + CINC*C2N*2) // f16 h[16][96][12544] = 38.5 MB

// ---------------- prep: fold BN into weights; Wp -> chunk-contiguous fragments --
// wpf[(((ksg)*6+rt)*64+lane)*8+e] = Wp[rt*16+(lane&15)][ksg*32+(lane>>4)*8+e]
// Wp[m][k] = w_pw[m][(k%64)*6 + k/64]  (channel shuffle groups=6 folded)
__global__ void k_prep(const float* __restrict__ wdw1, const float* __restrict__ g1,
                       const float* __restrict__ bb1, const float* __restrict__ m1,
                       const float* __restrict__ v1,
                       const float* __restrict__ wdw2, const float* __restrict__ g2,
                       const float* __restrict__ bb2, const float* __restrict__ m2,
                       const float* __restrict__ v2,
                       const float* __restrict__ wpw, const float* __restrict__ g3,
                       const float* __restrict__ bb3, const float* __restrict__ m3,
                       const float* __restrict__ v3,
                       float* ws)
{
    int t = blockIdx.x * blockDim.x + threadIdx.x;
    int stride = gridDim.x * blockDim.x;
    float* w1f = ws + WS_W1F; float* b1f = ws + WS_B1F;
    float* w2f = ws + WS_W2F; float* b2f = ws + WS_B2F;
    float* s3  = ws + WS_S3;  float* b3f = ws + WS_B3;
    _Float16* wpf = (_Float16*)((char*)ws + WS_WPF_BYTES);

    for (int c = t; c < C1N; c += stride) {
        float s = g1[c] / sqrtf(v1[c] + EPSV);
        w1f[c*3+0] = wdw1[c*3+0] * s;
        w1f[c*3+1] = wdw1[c*3+1] * s;
        w1f[c*3+2] = wdw1[c*3+2] * s;
        b1f[c] = bb1[c] - m1[c] * s;
    }
    for (int c = t; c < C2N; c += stride) {
        float s = g2[c] / sqrtf(v2[c] + EPSV);
        w2f[c*3+0] = wdw2[c*3+0] * s;
        w2f[c*3+1] = wdw2[c*3+1] * s;
        w2f[c*3+2] = wdw2[c*3+2] * s;
        b2f[c] = bb2[c] - m2[c] * s;
    }
    for (int c = t; c < CINC; c += stride) {
        float s = g3[c] / sqrtf(v3[c] + EPSV);
        s3[c] = s; b3f[c] = bb3[c] - m3[c] * s;
    }
    for (int idx = t; idx < CINC * C2N; idx += stride) {
        int e = idx & 7;
        int l2 = idx >> 3;
        int lane = l2 & 63;
        int l3 = l2 >> 6;
        int rt = l3 % 6, ksg = l3 / 6;
        int m = rt * 16 + (lane & 15);
        int k = ksg * 32 + (lane >> 4) * 8 + e;
        int o = (k & 63) * 6 + (k >> 6);
        wpf[idx] = (_Float16)wpw[m * C2N + o];
    }
}

// ---------------- main: float4 separable dw -> LDS-staged Wp MFMA -> h+sums ----
// block = 4 rows x 64 cols; thread = (row r, 4-col group c4); wave = 1 channel/iter
__global__ __launch_bounds__(256, 2) void k_main5(const float* __restrict__ x,
                                                  const float* __restrict__ ws,
                                                  float* __restrict__ sums,
                                                  _Float16* __restrict__ h_out)
{
    __shared__ __align__(16) char u_raw[256 * 208];   // u tile, slot-rotated (53248 B)
    __shared__ __align__(16) f16x8 wpf_s[1152];       // Wp chunk fragments (18432 B)
    __shared__ float ssum[CINC];

    int t   = threadIdx.x;
    int bid = blockIdx.x;
    int logical = (bid & 7) * 112 + (bid >> 3);       // XCD-chunked (896 = 8*112)
    int b   = logical / 56;
    int rem = logical - b * 56;
    int y0  = (rem >> 1) * 4;
    int x0  = (rem & 1) * 48;

    int wv = t >> 6, lane = t & 63;
    int r = lane >> 4, c4 = lane & 15;
    int gy = y0 + r;
    int gc = x0 + 4 * c4;
    int col16 = c4, g = r;                            // MFMA-phase aliases

    const float* w1f = ws + WS_W1F; const float* b1f = ws + WS_B1F;
    const float* w2f = ws + WS_W2F; const float* b2f = ws + WS_B2F;

    if (t < CINC) ssum[t] = 0.f;

    bool ymok = gy >= 1;
    bool ypok = gy + 1 < HGT;
    bool isE  = (c4 == 0) | (c4 == 15);
    int  ecol = (c4 == 0) ? (x0 - 1) : (x0 + 64);
    bool ev   = isE && ((unsigned)ecol < (unsigned)WID);
    int  secol = ev ? ecol : 0;
    int  tm = ymok ? -WID : 0;
    int  tp = ypok ?  WID : 0;

    f32x4 acc[6][4];
    #pragma unroll
    for (int rt = 0; rt < 6; ++rt)
        #pragma unroll
        for (int ct = 0; ct < 4; ++ct) acc[rt][ct] = (f32x4){0.f, 0.f, 0.f, 0.f};

    const f16x8* wpf_g = (const f16x8*)((const char*)ws + WS_WPF_BYTES);
    long xb = (long)b * CINC * HW;
    long rowoff = (long)gy * WID;

    for (int chunk = 0; chunk < 4; ++chunk) {
        if (chunk) __syncthreads();       // prev MFMA reads done before overwrite

        // stage this chunk's Wp fragments into LDS (overlaps gather below)
        #pragma unroll
        for (int j = 0; j < 5; ++j) {
            int idx = t + j * 256;
            if (idx < 1152) wpf_s[idx] = wpf_g[chunk * 1152 + idx];
        }

        // gather: 6 channels per wave, 4 cols per thread
        #pragma unroll 2
        for (int i = 0; i < 6; ++i) {
            int cl = wv * 6 + i;
            int cu = __builtin_amdgcn_readfirstlane(chunk * 24 + cl);
            const float* xc = x + xb + (long)cu * HW;
            const float* xp = xc + rowoff + gc;
            f32x4 mid = *(const f32x4*)xp;
            f32x4 top = *(const f32x4*)(xp + tm);
            f32x4 bot = *(const f32x4*)(xp + tp);

            float eT = 0.f, eM = 0.f, eB = 0.f;
            if (isE) {
                const float* ep = xc + rowoff + secol;
                eM = ep[0];
                eT = ep[tm];
                eB = ep[tp];
            }

            int c1a = cu * 2;
            float wa0 = w1f[c1a*3+0], wa1 = w1f[c1a*3+1], wa2 = w1f[c1a*3+2], ba = b1f[c1a];
            float wb0 = w1f[c1a*3+3], wb1 = w1f[c1a*3+4], wb2 = w1f[c1a*3+5], bb = b1f[c1a+1];

            float va[4], vb[4];
            #pragma unroll
            for (int j = 0; j < 4; ++j) {
                float tt = ymok ? top[j] : 0.f;
                float bt = ypok ? bot[j] : 0.f;
                va[j] = fmaf(wa0, tt, fmaf(wa1, mid[j], fmaf(wa2, bt, ba)));
                vb[j] = fmaf(wb0, tt, fmaf(wb1, mid[j], fmaf(wb2, bt, bb)));
            }
            // edge column v (zero when edge col outside image: conv2 zero-pads BN1 out)
            float etS = (ymok && ev) ? eT : 0.f;
            float ebS = (ypok && ev) ? eB : 0.f;
            float emS = ev ? eM : 0.f;
            float vea = ev ? fmaf(wa0, etS, fmaf(wa1, emS, fmaf(wa2, ebS, ba))) : 0.f;
            float veb = ev ? fmaf(wb0, etS, fmaf(wb1, emS, fmaf(wb2, ebS, bb))) : 0.f;

            float vLa = __shfl(va[3], (lane + 63) & 63);
            float vLb = __shfl(vb[3], (lane + 63) & 63);
            float vRa = __shfl(va[0], (lane + 1) & 63);
            float vRb = __shfl(vb[0], (lane + 1) & 63);
            if (c4 == 0)  { vLa = vea; vLb = veb; }
            if (c4 == 15) { vRa = vea; vRb = veb; }

            int c2b = cu * 4;
            float w20[4], w21[4], w22[4], b2v[4];
            #pragma unroll
            for (int jj = 0; jj < 4; ++jj) {
                w20[jj] = w2f[(c2b+jj)*3+0];
                w21[jj] = w2f[(c2b+jj)*3+1];
                w22[jj] = w2f[(c2b+jj)*3+2];
                b2v[jj] = b2f[c2b+jj];
            }

            float pa[6] = {vLa, va[0], va[1], va[2], va[3], vRa};
            float pb[6] = {vLb, vb[0], vb[1], vb[2], vb[3], vRb};
            // u slot: (k>>3 + 3*row + pos_c4) % 12  (applied identically on read)
            int slot = ((cl >> 1) + 3 * r + c4) % 12;
            int off8 = (cl & 1) * 8;
            char* ubase = u_raw + (r * 64 + 4 * c4) * 208 + slot * 16 + off8;
            #pragma unroll
            for (int j = 0; j < 4; ++j) {
                f16x4 uv;
                #pragma unroll
                for (int jj = 0; jj < 4; ++jj) {
                    float p0 = (jj < 2) ? pa[j]     : pb[j];
                    float p1 = (jj < 2) ? pa[j + 1] : pb[j + 1];
                    float p2 = (jj < 2) ? pa[j + 2] : pb[j + 2];
                    float tv = fmaf(w20[jj], p0, fmaf(w21[jj], p1, fmaf(w22[jj], p2, b2v[jj])));
                    tv = fminf(fmaxf(tv, 0.f), 6.f);
                    uv[jj] = (_Float16)tv;
                }
                *(f16x4*)(ubase + j * 208) = uv;
            }
        }
        __syncthreads();   // u + wpf_s ready

        // MFMA: acc += Wp[:, chunk slice] * u   (all operands in LDS)
        #pragma unroll
        for (int ks = 0; ks < 3; ++ks) {
            f16x8 bfr[4];
            #pragma unroll
            for (int ct = 0; ct < 4; ++ct) {
                int pos = wv * 64 + ct * 16 + col16;
                int sl = (ks * 4 + g + 3 * wv + ((pos >> 2) & 15)) % 12;
                bfr[ct] = *(const f16x8*)(u_raw + pos * 208 + sl * 16);
            }
            #pragma unroll
            for (int rt = 0; rt < 6; ++rt) {
                f16x8 afr = wpf_s[(ks * 6 + rt) * 64 + lane];
                #pragma unroll
                for (int ct = 0; ct < 4; ++ct)
                    acc[rt][ct] = __builtin_amdgcn_mfma_f32_16x16x32_f16(afr, bfr[ct], acc[rt][ct], 0, 0, 0);
            }
        }
    }
    __syncthreads();   // last MFMA reads done before aliasing u_raw with h

    // stage h (bn3, f16) into LDS: h_s[m][264]
    _Float16* h_s = (_Float16*)u_raw;
    const float* s3  = ws + WS_S3;
    const float* b3f = ws + WS_B3;
    #pragma unroll
    for (int rt = 0; rt < 6; ++rt) {
        #pragma unroll
        for (int ct = 0; ct < 4; ++ct) {
            int p = wv * 64 + ct * 16 + col16;
            #pragma unroll
            for (int rr = 0; rr < 4; ++rr) {
                int m = rt * 16 + g * 4 + rr;
                h_s[m * 264 + p] = (_Float16)fmaf(acc[rt][ct][rr], s3[m], b3f[m]);
            }
        }
    }
    __syncthreads();

    // coalesced full-line h stores + channel sums (overlap cols masked)
    #pragma unroll
    for (int i = 0; i < 12; ++i) {
        int flat = i * 2048 + t * 8;           // covers 96*256 exactly
        int m = flat >> 8;
        int p = flat & 255;
        f16x8 hv = *(const f16x8*)(h_s + m * 264 + p);
        int row = y0 + (p >> 6);
        int colg = x0 + (p & 63);
        *(f16x8*)(h_out + ((long)(b * CINC + m)) * HW + (long)row * WID + colg) = hv;

        float s = 0.f;
        if (!(x0 == 48 && (p & 63) < 16)) {    // overlap cols 48..63 counted by half-0
            #pragma unroll
            for (int e = 0; e < 8; ++e) s += (float)hv[e];
        }
        s += __shfl_xor(s, 1);
        s += __shfl_xor(s, 2);
        s += __shfl_xor(s, 4);
        s += __shfl_xor(s, 8);
        s += __shfl_xor(s, 16);
        if ((lane & 31) == 0) atomicAdd(&ssum[m], s);
    }
    __syncthreads();
    if (t < CINC) atomicAdd(&sums[b * CINC + t], ssum[t]);
}

// ---------------- gates: mean(h) -> fc1+relu -> fc2 -> hardsig -> a1,b1 -------
__global__ __launch_bounds__(192) void k_gates(const float* __restrict__ sums,
                                               const float* __restrict__ fc1w,
                                               const float* __restrict__ fc1b,
                                               const float* __restrict__ fc2w,
                                               const float* __restrict__ fc2b,
                                               float* __restrict__ a1b1)
{
    __shared__ float mean_s[CINC];
    __shared__ float mid[24];
    int b = blockIdx.x;
    int t = threadIdx.x;     // 192

    if (t < CINC) mean_s[t] = sums[b * CINC + t] * (1.0f / 12544.0f);
    __syncthreads();
    if (t < 24) {
        float d = fc1b[t];
        #pragma unroll 4
        for (int c = 0; c < CINC; ++c) d = fmaf(fc1w[t * CINC + c], mean_s[c], d);
        mid[t] = fmaxf(d, 0.f);
    }
    __syncthreads();
    {
        float d = fc2b[t];
        #pragma unroll
        for (int j = 0; j < 24; ++j) d = fmaf(fc2w[t * 24 + j], mid[j], d);
        float y = fminf(fmaxf(d + 3.f, 0.f), 6.f) * (1.f / 6.f);
        y = (y - 0.5f) * 4.f;
        a1b1[b * 192 + t] = (t < CINC) ? (y + 1.f) : y;
    }
}

// ---------------- final: h*a1 + roll(h)*b1, shuffle(48), + x (pure streaming) --
__global__ __launch_bounds__(256) void k_final(const _Float16* __restrict__ h,
                                               const float* __restrict__ xin,
                                               const float* __restrict__ a1b1,
                                               float* __restrict__ out)
{
    int q = blockIdx.x * 256 + threadIdx.x;      // 4,816,896 quads total (exact)
    int pos4 = q % 3136;
    int bo = q / 3136;
    int o = bo % CINC, b = bo / CINC;
    int c = (o % 48) * 2 + (o / 48);             // shuffle(48) folded
    int cn = (c + 1) % CINC;                      // channel roll

    float av = a1b1[b * 192 + c];
    float bv = a1b1[b * 192 + 96 + c];

    long hb = (long)b * CINC * HW;
    f16x4 hv4 = *(const f16x4*)(h + hb + (long)c  * HW + pos4 * 4);
    f16x4 h2v = *(const f16x4*)(h + hb + (long)cn * HW + pos4 * 4);

    long xo = ((long)(b * CINC + o)) * HW + pos4 * 4;
    f32x4 xv = *(const f32x4*)(xin + xo);
    f32x4 rr;
    #pragma unroll
    for (int j = 0; j < 4; ++j)
        rr[j] = fmaf((float)hv4[j], av, fmaf((float)h2v[j], bv, xv[j]));
    *(f32x4*)(out + xo) = rr;
}

extern "C" void kernel_launch(void* const* d_in, const int* in_sizes, int n_in,
                              void* d_out, int out_size, void* d_ws, size_t ws_size,
                              hipStream_t stream)
{
    const float* x    = (const float*)d_in[0];
    const float* wdw1 = (const float*)d_in[1];
    const float* g1   = (const float*)d_in[2];
    const float* b1   = (const float*)d_in[3];
    const float* m1   = (const float*)d_in[4];
    const float* v1   = (const float*)d_in[5];
    const float* wdw2 = (const float*)d_in[6];
    const float* g2   = (const float*)d_in[7];
    const float* b2   = (const float*)d_in[8];
    const float* m2   = (const float*)d_in[9];
    const float* v2   = (const float*)d_in[10];
    const float* wpw  = (const float*)d_in[11];
    const float* g3   = (const float*)d_in[12];
    const float* b3   = (const float*)d_in[13];
    const float* m3   = (const float*)d_in[14];
    const float* v3   = (const float*)d_in[15];
    const float* fc1w = (const float*)d_in[16];
    const float* fc1b = (const float*)d_in[17];
    const float* fc2w = (const float*)d_in[18];
    const float* fc2b = (const float*)d_in[19];

    float* ws   = (float*)d_ws;
    float* sums = ws + WS_S;
    float* a1b1 = ws + WS_A1B1;
    _Float16* hbuf = (_Float16*)((char*)d_ws + WS_H_BYTES);
    float* out  = (float*)d_out;

    hipMemsetAsync(sums, 0, 1536 * sizeof(float), stream);
    k_prep<<<dim3(40), dim3(256), 0, stream>>>(
        wdw1, g1, b1, m1, v1, wdw2, g2, b2, m2, v2,
        wpw, g3, b3, m3, v3, ws);
    k_main5<<<dim3(896), dim3(256), 0, stream>>>(x, ws, sums, hbuf);
    k_gates<<<dim3(BATCH), dim3(192), 0, stream>>>(sums, fc1w, fc1b, fc2w, fc2b, a1b1);
    k_final<<<dim3(4816896 / 256), dim3(256), 0, stream>>>(hbuf, x, a1b1, out);
}